// Round 4
// baseline (94.951 us; speedup 1.0000x reference)
//
#include <hip/hip_runtime.h>
#include <math.h>

#define EPS 1e-8f

constexpr int B = 32, N = 1024, M = 128, H = 2;

constexpr int ROWS_A   = 16;            // rows of L (and mem) per block
constexpr int CHUNKS_A = N / ROWS_A;    // 64
constexpr int NBLK_A   = B * CHUNKS_A;  // 2048
constexpr int ROWS_C   = 64;            // rows per k2 block
constexpr int CHUNKS_C = N / ROWS_C;    // 16

typedef float floatx4 __attribute__((ext_vector_type(4)));

// ---- K1: per block (b, chunk): f/bpart over 16 L-rows  AND  e over 16 mem-rows.
__global__ __launch_bounds__(256) void k1(const float* __restrict__ L,
                                          const float* __restrict__ Wold,
                                          const float* __restrict__ mem,
                                          const float* __restrict__ keys,
                                          const float* __restrict__ strengths,
                                          const int* __restrict__ head,
                                          float* __restrict__ f,
                                          float* __restrict__ bpart,
                                          float* __restrict__ e) {
    int bid   = blockIdx.x;
    int t     = threadIdx.x;
    int lane  = t & 63, wave = t >> 6;
    int b     = bid / CHUNKS_A;
    int chunk = bid % CHUNKS_A;
    int r0    = chunk * ROWS_A;

    __shared__ float sw[N];
    __shared__ float lds_b[4][N];

    reinterpret_cast<float4*>(sw)[t] =
        reinterpret_cast<const float4*>(Wold + (size_t)b * N)[t];
    __syncthreads();

    float4 wreg[4];
    float4 bacc[4];
#pragma unroll
    for (int s = 0; s < 4; ++s) {
        wreg[s] = reinterpret_cast<float4*>(sw)[lane + 64 * s];
        bacc[s] = make_float4(0.f, 0.f, 0.f, 0.f);
    }

    const float* Lb = L + (size_t)b * N * N;
    for (int r = wave; r < ROWS_A; r += 4) {          // 4 rows per wave
        int i = r0 + r;
        const floatx4* row = reinterpret_cast<const floatx4*>(Lb + (size_t)i * N);
        float wi = sw[i];
        float p  = 0.f;
#pragma unroll
        for (int s = 0; s < 4; ++s) {
            floatx4 v = __builtin_nontemporal_load(row + lane + 64 * s);
            p += v.x * wreg[s].x + v.y * wreg[s].y + v.z * wreg[s].z + v.w * wreg[s].w;
            bacc[s].x += v.x * wi;
            bacc[s].y += v.y * wi;
            bacc[s].z += v.z * wi;
            bacc[s].w += v.w * wi;
        }
#pragma unroll
        for (int off = 32; off; off >>= 1) p += __shfl_down(p, off, 64);
        if (lane == 0) f[(size_t)b * N + i] = p;
    }

    // e-work: same 16 rows of memory
    {
        int l32 = lane & 31, half = lane >> 5;
        int h   = head[0];
        float4 kv = reinterpret_cast<const float4*>(keys + ((size_t)b * H + h) * M)[l32];
        float  sk = kv.x * kv.x + kv.y * kv.y + kv.z * kv.z + kv.w * kv.w;
#pragma unroll
        for (int off = 16; off; off >>= 1) sk += __shfl_xor(sk, off, 64);
        float norm_k = sqrtf(sk);
        float beta   = strengths[(size_t)b * H + h];
#pragma unroll
        for (int rr = 0; rr < ROWS_A / 8; ++rr) {     // 2 iters, 2 rows/wave/iter
            int n = r0 + wave * 4 + rr * 2 + half;
            float4 mv = reinterpret_cast<const float4*>(mem + ((size_t)b * N + n) * M)[l32];
            float dot = mv.x * kv.x + mv.y * kv.y + mv.z * kv.z + mv.w * kv.w;
            float sm  = mv.x * mv.x + mv.y * mv.y + mv.z * mv.z + mv.w * mv.w;
#pragma unroll
            for (int off = 16; off; off >>= 1) {
                dot += __shfl_xor(dot, off, 64);
                sm  += __shfl_xor(sm, off, 64);
            }
            if (l32 == 0) {
                float denom = sqrtf(sm) * norm_k + EPS;
                e[(size_t)b * N + n] = expf(beta * dot / denom);
            }
        }
    }

#pragma unroll
    for (int s = 0; s < 4; ++s)
        reinterpret_cast<float4*>(lds_b[wave])[lane + 64 * s] = bacc[s];
    __syncthreads();

    float4 s0 = reinterpret_cast<float4*>(lds_b[0])[t];
    float4 s1 = reinterpret_cast<float4*>(lds_b[1])[t];
    float4 s2 = reinterpret_cast<float4*>(lds_b[2])[t];
    float4 s3 = reinterpret_cast<float4*>(lds_b[3])[t];
    float4 o;
    o.x = s0.x + s1.x + s2.x + s3.x;
    o.y = s0.y + s1.y + s2.y + s3.y;
    o.z = s0.z + s1.z + s2.z + s3.z;
    o.w = s0.w + s1.w + s2.w + s3.w;
    reinterpret_cast<float4*>(bpart + ((size_t)b * CHUNKS_A + chunk) * N)[t] = o;
}

// ---- K2: per 64-row chunk: bsum, U = rm0*bsum + rm2*f, partial mcU/mcE/epart,
// ----     then last-block-per-batch finalizes W and mem_content.
__global__ __launch_bounds__(256) void k2(const float* __restrict__ mem,
                                          const float* __restrict__ bpart,
                                          const float* __restrict__ f,
                                          const float* __restrict__ e,
                                          const float* __restrict__ mode,
                                          const int* __restrict__ head,
                                          float* __restrict__ U,
                                          float* __restrict__ mcU,
                                          float* __restrict__ mcE,
                                          float* __restrict__ epart,
                                          unsigned int* __restrict__ ctr,
                                          float* __restrict__ outW,
                                          float* __restrict__ outMC) {
    int bid   = blockIdx.x;
    int b     = bid / CHUNKS_C;
    int chunk = bid % CHUNKS_C;
    int t     = threadIdx.x;
    int r0    = chunk * ROWS_C;

    __shared__ float bp[4][ROWS_C];
    __shared__ float su[ROWS_C], se[ROWS_C];
    __shared__ float4 lU[8][32];
    __shared__ float4 lE[8][32];
    __shared__ unsigned int sOld;

    // phase 1: bsum partials over CHUNKS_A, split across 4 c-groups
    int n_ = t & 63, cg_ = t >> 6;
    float s = 0.f;
    for (int c = cg_; c < CHUNKS_A; c += 4)
        s += bpart[((size_t)b * CHUNKS_A + c) * N + r0 + n_];
    bp[cg_][n_] = s;
    __syncthreads();

    int h = head[0];
    const float* rm = mode + ((size_t)b * H + h) * 3;
    if (t < ROWS_C) {
        float bsum = bp[0][t] + bp[1][t] + bp[2][t] + bp[3][t];
        float u = rm[0] * bsum + rm[2] * f[(size_t)b * N + r0 + t];
        su[t] = u;
        U[(size_t)b * N + r0 + t] = u;
        se[t] = e[(size_t)b * N + r0 + t];
    }
    __syncthreads();

    // phase 2: mc partials
    int cg = t & 31, rg = t >> 5;
    float4 aU = make_float4(0.f, 0.f, 0.f, 0.f);
    float4 aE = make_float4(0.f, 0.f, 0.f, 0.f);
#pragma unroll
    for (int rr = 0; rr < ROWS_C / 8; ++rr) {
        int r = rg + rr * 8;
        float4 v = reinterpret_cast<const float4*>(mem + ((size_t)b * N + r0 + r) * M)[cg];
        float uu = su[r], ee = se[r];
        aU.x += uu * v.x; aU.y += uu * v.y; aU.z += uu * v.z; aU.w += uu * v.w;
        aE.x += ee * v.x; aE.y += ee * v.y; aE.z += ee * v.z; aE.w += ee * v.w;
    }
    lU[rg][cg] = aU;
    lE[rg][cg] = aE;
    __syncthreads();

    if (t < 32) {
        float4 oU = make_float4(0.f, 0.f, 0.f, 0.f);
        float4 oE = make_float4(0.f, 0.f, 0.f, 0.f);
#pragma unroll
        for (int g = 0; g < 8; ++g) {
            float4 vU = lU[g][t], vE = lE[g][t];
            oU.x += vU.x; oU.y += vU.y; oU.z += vU.z; oU.w += vU.w;
            oE.x += vE.x; oE.y += vE.y; oE.z += vE.z; oE.w += vE.w;
        }
        reinterpret_cast<float4*>(mcU + ((size_t)b * CHUNKS_C + chunk) * M)[t] = oU;
        reinterpret_cast<float4*>(mcE + ((size_t)b * CHUNKS_C + chunk) * M)[t] = oE;
    } else if (t >= 64 && t < 128) {
        float val = se[t - 64];
#pragma unroll
        for (int off = 32; off; off >>= 1) val += __shfl_down(val, off, 64);
        if (t == 64) epart[(size_t)b * CHUNKS_C + chunk] = val;
    }

    // ---- last block of this batch finalizes ----
    __threadfence();
    __syncthreads();
    if (t == 0) sOld = atomicAdd(&ctr[b], 1u);
    __syncthreads();
    if (sOld == CHUNKS_C - 1) {
        __threadfence();
        float S = 0.f;
#pragma unroll
        for (int c = 0; c < CHUNKS_C; ++c) S += epart[(size_t)b * CHUNKS_C + c];
        float coef = rm[1] / S;

        float4 u  = reinterpret_cast<const float4*>(U + (size_t)b * N)[t];
        float4 ev = reinterpret_cast<const float4*>(e + (size_t)b * N)[t];
        float4 o;
        o.x = u.x + coef * ev.x;
        o.y = u.y + coef * ev.y;
        o.z = u.z + coef * ev.z;
        o.w = u.w + coef * ev.w;
        reinterpret_cast<float4*>(outW + (size_t)b * N)[t] = o;

        if (t < M) {
            float sU = 0.f, sE = 0.f;
#pragma unroll
            for (int c = 0; c < CHUNKS_C; ++c) {
                sU += mcU[((size_t)b * CHUNKS_C + c) * M + t];
                sE += mcE[((size_t)b * CHUNKS_C + c) * M + t];
            }
            outMC[(size_t)b * M + t] = sU + coef * sE;
        }
    }
}

extern "C" void kernel_launch(void* const* d_in, const int* in_sizes, int n_in,
                              void* d_out, int out_size, void* d_ws, size_t ws_size,
                              hipStream_t stream) {
    const float* read_keys      = (const float*)d_in[0];
    const float* read_strengths = (const float*)d_in[1];
    const float* read_mode      = (const float*)d_in[2];
    const float* W_old          = (const float*)d_in[3];
    const float* L              = (const float*)d_in[4];
    const float* memory         = (const float*)d_in[5];
    const int*   head_no        = (const int*)d_in[6];

    float* out_W  = (float*)d_out;             // B*N
    float* out_mc = out_W + (size_t)B * N;     // B*M

    float* ws    = (float*)d_ws;
    float* f     = ws;                                    // B*N
    float* bpart = f + (size_t)B * N;                     // B*CHUNKS_A*N (8 MB)
    float* e     = bpart + (size_t)B * CHUNKS_A * N;      // B*N
    float* Ubuf  = e + (size_t)B * N;                     // B*N
    float* mcU   = Ubuf + (size_t)B * N;                  // B*CHUNKS_C*M
    float* mcE   = mcU + (size_t)B * CHUNKS_C * M;        // B*CHUNKS_C*M
    float* epart = mcE + (size_t)B * CHUNKS_C * M;        // B*CHUNKS_C
    unsigned int* ctr = (unsigned int*)(epart + (size_t)B * CHUNKS_C);  // B

    (void)hipMemsetAsync(ctr, 0, B * sizeof(unsigned int), stream);
    k1<<<NBLK_A, 256, 0, stream>>>(L, W_old, memory, read_keys,
                                   read_strengths, head_no, f, bpart, e);
    k2<<<B * CHUNKS_C, 256, 0, stream>>>(memory, bpart, f, e, read_mode, head_no,
                                         Ubuf, mcU, mcE, epart, ctr, out_W, out_mc);
}

// Round 5
// 86.990 us; speedup vs baseline: 1.0915x; 1.0915x over previous
//
#include <hip/hip_runtime.h>
#include <math.h>

#define EPS 1e-8f

constexpr int B = 32, N = 1024, M = 128, H = 2;

constexpr int ROWS_A   = 16;            // rows of L (and mem) per block
constexpr int CHUNKS_A = N / ROWS_A;    // 64
constexpr int NBLK_A   = B * CHUNKS_A;  // 2048
constexpr int ROWS_C   = 64;            // rows per k2 block
constexpr int CHUNKS_C = N / ROWS_C;    // 16

// ---- K1: per block (b, chunk): f/bpart over 16 L-rows AND e over 16 mem-rows.
// ----     Block 0 also zeroes the k2 completion counters (k1 finishes before k2 starts).
__global__ __launch_bounds__(256) void k1(const float* __restrict__ L,
                                          const float* __restrict__ Wold,
                                          const float* __restrict__ mem,
                                          const float* __restrict__ keys,
                                          const float* __restrict__ strengths,
                                          const int* __restrict__ head,
                                          float* __restrict__ f,
                                          float* __restrict__ bpart,
                                          float* __restrict__ e,
                                          unsigned int* __restrict__ ctr) {
    int bid   = blockIdx.x;
    int t     = threadIdx.x;
    int lane  = t & 63, wave = t >> 6;
    int b     = bid / CHUNKS_A;
    int chunk = bid % CHUNKS_A;
    int r0    = chunk * ROWS_A;

    if (bid == 0 && t < B) ctr[t] = 0u;

    __shared__ float sw[N];
    __shared__ float lds_b[4][N];

    reinterpret_cast<float4*>(sw)[t] =
        reinterpret_cast<const float4*>(Wold + (size_t)b * N)[t];
    __syncthreads();

    float4 wreg[4];
    float4 bacc[4];
#pragma unroll
    for (int s = 0; s < 4; ++s) {
        wreg[s] = reinterpret_cast<float4*>(sw)[lane + 64 * s];
        bacc[s] = make_float4(0.f, 0.f, 0.f, 0.f);
    }

    const float* Lb = L + (size_t)b * N * N;
    for (int r = wave; r < ROWS_A; r += 4) {          // 4 rows per wave
        int i = r0 + r;
        const float4* row = reinterpret_cast<const float4*>(Lb + (size_t)i * N);
        float wi = sw[i];
        float p  = 0.f;
#pragma unroll
        for (int s = 0; s < 4; ++s) {
            float4 v = row[lane + 64 * s];
            p += v.x * wreg[s].x + v.y * wreg[s].y + v.z * wreg[s].z + v.w * wreg[s].w;
            bacc[s].x += v.x * wi;
            bacc[s].y += v.y * wi;
            bacc[s].z += v.z * wi;
            bacc[s].w += v.w * wi;
        }
#pragma unroll
        for (int off = 32; off; off >>= 1) p += __shfl_down(p, off, 64);
        if (lane == 0) f[(size_t)b * N + i] = p;
    }

    // e-work: same 16 rows of memory
    {
        int l32 = lane & 31, half = lane >> 5;
        int h   = head[0];
        float4 kv = reinterpret_cast<const float4*>(keys + ((size_t)b * H + h) * M)[l32];
        float  sk = kv.x * kv.x + kv.y * kv.y + kv.z * kv.z + kv.w * kv.w;
#pragma unroll
        for (int off = 16; off; off >>= 1) sk += __shfl_xor(sk, off, 64);
        float norm_k = sqrtf(sk);
        float beta   = strengths[(size_t)b * H + h];
#pragma unroll
        for (int rr = 0; rr < ROWS_A / 8; ++rr) {     // 2 iters, 2 rows/wave/iter
            int n = r0 + wave * 4 + rr * 2 + half;
            float4 mv = reinterpret_cast<const float4*>(mem + ((size_t)b * N + n) * M)[l32];
            float dot = mv.x * kv.x + mv.y * kv.y + mv.z * kv.z + mv.w * kv.w;
            float sm  = mv.x * mv.x + mv.y * mv.y + mv.z * mv.z + mv.w * mv.w;
#pragma unroll
            for (int off = 16; off; off >>= 1) {
                dot += __shfl_xor(dot, off, 64);
                sm  += __shfl_xor(sm, off, 64);
            }
            if (l32 == 0) {
                float denom = sqrtf(sm) * norm_k + EPS;
                e[(size_t)b * N + n] = expf(beta * dot / denom);
            }
        }
    }

#pragma unroll
    for (int s = 0; s < 4; ++s)
        reinterpret_cast<float4*>(lds_b[wave])[lane + 64 * s] = bacc[s];
    __syncthreads();

    float4 s0 = reinterpret_cast<float4*>(lds_b[0])[t];
    float4 s1 = reinterpret_cast<float4*>(lds_b[1])[t];
    float4 s2 = reinterpret_cast<float4*>(lds_b[2])[t];
    float4 s3 = reinterpret_cast<float4*>(lds_b[3])[t];
    float4 o;
    o.x = s0.x + s1.x + s2.x + s3.x;
    o.y = s0.y + s1.y + s2.y + s3.y;
    o.z = s0.z + s1.z + s2.z + s3.z;
    o.w = s0.w + s1.w + s2.w + s3.w;
    reinterpret_cast<float4*>(bpart + ((size_t)b * CHUNKS_A + chunk) * N)[t] = o;
}

// ---- K2: per 64-row chunk: bsum, U = rm0*bsum + rm2*f, partial mcU/mcE/epart,
// ----     then last-block-per-batch finalizes W and mem_content.
__global__ __launch_bounds__(256) void k2(const float* __restrict__ mem,
                                          const float* __restrict__ bpart,
                                          const float* __restrict__ f,
                                          const float* __restrict__ e,
                                          const float* __restrict__ mode,
                                          const int* __restrict__ head,
                                          float* __restrict__ U,
                                          float* __restrict__ mcU,
                                          float* __restrict__ mcE,
                                          float* __restrict__ epart,
                                          unsigned int* __restrict__ ctr,
                                          float* __restrict__ outW,
                                          float* __restrict__ outMC) {
    int bid   = blockIdx.x;
    int b     = bid / CHUNKS_C;
    int chunk = bid % CHUNKS_C;
    int t     = threadIdx.x;
    int r0    = chunk * ROWS_C;

    __shared__ float bp[4][ROWS_C];
    __shared__ float su[ROWS_C], se[ROWS_C];
    __shared__ float4 lU[8][32];
    __shared__ float4 lE[8][32];
    __shared__ unsigned int sOld;

    // phase 1: bsum partials over CHUNKS_A, split across 4 c-groups
    int n_ = t & 63, cg_ = t >> 6;
    float s = 0.f;
    for (int c = cg_; c < CHUNKS_A; c += 4)
        s += bpart[((size_t)b * CHUNKS_A + c) * N + r0 + n_];
    bp[cg_][n_] = s;
    __syncthreads();

    int h = head[0];
    const float* rm = mode + ((size_t)b * H + h) * 3;
    if (t < ROWS_C) {
        float bsum = bp[0][t] + bp[1][t] + bp[2][t] + bp[3][t];
        float u = rm[0] * bsum + rm[2] * f[(size_t)b * N + r0 + t];
        su[t] = u;
        U[(size_t)b * N + r0 + t] = u;
        se[t] = e[(size_t)b * N + r0 + t];
    }
    __syncthreads();

    // phase 2: mc partials
    int cg = t & 31, rg = t >> 5;
    float4 aU = make_float4(0.f, 0.f, 0.f, 0.f);
    float4 aE = make_float4(0.f, 0.f, 0.f, 0.f);
#pragma unroll
    for (int rr = 0; rr < ROWS_C / 8; ++rr) {
        int r = rg + rr * 8;
        float4 v = reinterpret_cast<const float4*>(mem + ((size_t)b * N + r0 + r) * M)[cg];
        float uu = su[r], ee = se[r];
        aU.x += uu * v.x; aU.y += uu * v.y; aU.z += uu * v.z; aU.w += uu * v.w;
        aE.x += ee * v.x; aE.y += ee * v.y; aE.z += ee * v.z; aE.w += ee * v.w;
    }
    lU[rg][cg] = aU;
    lE[rg][cg] = aE;
    __syncthreads();

    if (t < 32) {
        float4 oU = make_float4(0.f, 0.f, 0.f, 0.f);
        float4 oE = make_float4(0.f, 0.f, 0.f, 0.f);
#pragma unroll
        for (int g = 0; g < 8; ++g) {
            float4 vU = lU[g][t], vE = lE[g][t];
            oU.x += vU.x; oU.y += vU.y; oU.z += vU.z; oU.w += vU.w;
            oE.x += vE.x; oE.y += vE.y; oE.z += vE.z; oE.w += vE.w;
        }
        reinterpret_cast<float4*>(mcU + ((size_t)b * CHUNKS_C + chunk) * M)[t] = oU;
        reinterpret_cast<float4*>(mcE + ((size_t)b * CHUNKS_C + chunk) * M)[t] = oE;
    } else if (t >= 64 && t < 128) {
        float val = se[t - 64];
#pragma unroll
        for (int off = 32; off; off >>= 1) val += __shfl_down(val, off, 64);
        if (t == 64) epart[(size_t)b * CHUNKS_C + chunk] = val;
    }

    // ---- last block of this batch finalizes ----
    __threadfence();
    __syncthreads();
    if (t == 0) sOld = atomicAdd(&ctr[b], 1u);
    __syncthreads();
    if (sOld == CHUNKS_C - 1) {
        __threadfence();
        float S = 0.f;
#pragma unroll
        for (int c = 0; c < CHUNKS_C; ++c) S += epart[(size_t)b * CHUNKS_C + c];
        float coef = rm[1] / S;

        float4 u  = reinterpret_cast<const float4*>(U + (size_t)b * N)[t];
        float4 ev = reinterpret_cast<const float4*>(e + (size_t)b * N)[t];
        float4 o;
        o.x = u.x + coef * ev.x;
        o.y = u.y + coef * ev.y;
        o.z = u.z + coef * ev.z;
        o.w = u.w + coef * ev.w;
        reinterpret_cast<float4*>(outW + (size_t)b * N)[t] = o;

        if (t < M) {
            float sU = 0.f, sE = 0.f;
#pragma unroll
            for (int c = 0; c < CHUNKS_C; ++c) {
                sU += mcU[((size_t)b * CHUNKS_C + c) * M + t];
                sE += mcE[((size_t)b * CHUNKS_C + c) * M + t];
            }
            outMC[(size_t)b * M + t] = sU + coef * sE;
        }
    }
}

extern "C" void kernel_launch(void* const* d_in, const int* in_sizes, int n_in,
                              void* d_out, int out_size, void* d_ws, size_t ws_size,
                              hipStream_t stream) {
    const float* read_keys      = (const float*)d_in[0];
    const float* read_strengths = (const float*)d_in[1];
    const float* read_mode      = (const float*)d_in[2];
    const float* W_old          = (const float*)d_in[3];
    const float* L              = (const float*)d_in[4];
    const float* memory         = (const float*)d_in[5];
    const int*   head_no        = (const int*)d_in[6];

    float* out_W  = (float*)d_out;             // B*N
    float* out_mc = out_W + (size_t)B * N;     // B*M

    float* ws    = (float*)d_ws;
    float* f     = ws;                                    // B*N
    float* bpart = f + (size_t)B * N;                     // B*CHUNKS_A*N (8 MB)
    float* e     = bpart + (size_t)B * CHUNKS_A * N;      // B*N
    float* Ubuf  = e + (size_t)B * N;                     // B*N
    float* mcU   = Ubuf + (size_t)B * N;                  // B*CHUNKS_C*M
    float* mcE   = mcU + (size_t)B * CHUNKS_C * M;        // B*CHUNKS_C*M
    float* epart = mcE + (size_t)B * CHUNKS_C * M;        // B*CHUNKS_C
    unsigned int* ctr = (unsigned int*)(epart + (size_t)B * CHUNKS_C);  // B

    k1<<<NBLK_A, 256, 0, stream>>>(L, W_old, memory, read_keys,
                                   read_strengths, head_no, f, bpart, e, ctr);
    k2<<<B * CHUNKS_C, 256, 0, stream>>>(memory, bpart, f, e, read_mode, head_no,
                                         Ubuf, mcU, mcE, epart, ctr, out_W, out_mc);
}

// Round 6
// 41.002 us; speedup vs baseline: 2.3158x; 2.1216x over previous
//
#include <hip/hip_runtime.h>
#include <math.h>

#define EPS 1e-8f

constexpr int B = 32, N = 1024, M = 128, H = 2;

constexpr int ROWS_A   = 16;            // rows of L (and mem) per block
constexpr int CHUNKS_A = N / ROWS_A;    // 64
constexpr int NBLK_A   = B * CHUNKS_A;  // 2048
constexpr int ROWS_C   = 64;            // rows per k2 block
constexpr int CHUNKS_C = N / ROWS_C;    // 16

// ---- K1: per block (b, chunk): f/bpart over 16 L-rows AND e over 16 mem-rows.
__global__ __launch_bounds__(256) void k1(const float* __restrict__ L,
                                          const float* __restrict__ Wold,
                                          const float* __restrict__ mem,
                                          const float* __restrict__ keys,
                                          const float* __restrict__ strengths,
                                          const int* __restrict__ head,
                                          float* __restrict__ f,
                                          float* __restrict__ bpart,
                                          float* __restrict__ e) {
    int bid   = blockIdx.x;
    int t     = threadIdx.x;
    int lane  = t & 63, wave = t >> 6;
    int b     = bid / CHUNKS_A;
    int chunk = bid % CHUNKS_A;
    int r0    = chunk * ROWS_A;

    __shared__ float sw[N];
    __shared__ float lds_b[4][N];

    reinterpret_cast<float4*>(sw)[t] =
        reinterpret_cast<const float4*>(Wold + (size_t)b * N)[t];
    __syncthreads();

    float4 wreg[4];
    float4 bacc[4];
#pragma unroll
    for (int s = 0; s < 4; ++s) {
        wreg[s] = reinterpret_cast<float4*>(sw)[lane + 64 * s];
        bacc[s] = make_float4(0.f, 0.f, 0.f, 0.f);
    }

    const float* Lb = L + (size_t)b * N * N;
    for (int r = wave; r < ROWS_A; r += 4) {          // 4 rows per wave
        int i = r0 + r;
        const float4* row = reinterpret_cast<const float4*>(Lb + (size_t)i * N);
        float wi = sw[i];
        float p  = 0.f;
#pragma unroll
        for (int s = 0; s < 4; ++s) {
            float4 v = row[lane + 64 * s];
            p += v.x * wreg[s].x + v.y * wreg[s].y + v.z * wreg[s].z + v.w * wreg[s].w;
            bacc[s].x += v.x * wi;
            bacc[s].y += v.y * wi;
            bacc[s].z += v.z * wi;
            bacc[s].w += v.w * wi;
        }
#pragma unroll
        for (int off = 32; off; off >>= 1) p += __shfl_down(p, off, 64);
        if (lane == 0) f[(size_t)b * N + i] = p;
    }

    // e-work: same 16 rows of memory
    {
        int l32 = lane & 31, half = lane >> 5;
        int h   = head[0];
        float4 kv = reinterpret_cast<const float4*>(keys + ((size_t)b * H + h) * M)[l32];
        float  sk = kv.x * kv.x + kv.y * kv.y + kv.z * kv.z + kv.w * kv.w;
#pragma unroll
        for (int off = 16; off; off >>= 1) sk += __shfl_xor(sk, off, 64);
        float norm_k = sqrtf(sk);
        float beta   = strengths[(size_t)b * H + h];
#pragma unroll
        for (int rr = 0; rr < ROWS_A / 8; ++rr) {     // 2 iters, 2 rows/wave/iter
            int n = r0 + wave * 4 + rr * 2 + half;
            float4 mv = reinterpret_cast<const float4*>(mem + ((size_t)b * N + n) * M)[l32];
            float dot = mv.x * kv.x + mv.y * kv.y + mv.z * kv.z + mv.w * kv.w;
            float sm  = mv.x * mv.x + mv.y * mv.y + mv.z * mv.z + mv.w * mv.w;
#pragma unroll
            for (int off = 16; off; off >>= 1) {
                dot += __shfl_xor(dot, off, 64);
                sm  += __shfl_xor(sm, off, 64);
            }
            if (l32 == 0) {
                float denom = sqrtf(sm) * norm_k + EPS;
                e[(size_t)b * N + n] = expf(beta * dot / denom);
            }
        }
    }

#pragma unroll
    for (int s = 0; s < 4; ++s)
        reinterpret_cast<float4*>(lds_b[wave])[lane + 64 * s] = bacc[s];
    __syncthreads();

    float4 s0 = reinterpret_cast<float4*>(lds_b[0])[t];
    float4 s1 = reinterpret_cast<float4*>(lds_b[1])[t];
    float4 s2 = reinterpret_cast<float4*>(lds_b[2])[t];
    float4 s3 = reinterpret_cast<float4*>(lds_b[3])[t];
    float4 o;
    o.x = s0.x + s1.x + s2.x + s3.x;
    o.y = s0.y + s1.y + s2.y + s3.y;
    o.z = s0.z + s1.z + s2.z + s3.z;
    o.w = s0.w + s1.w + s2.w + s3.w;
    reinterpret_cast<float4*>(bpart + ((size_t)b * CHUNKS_A + chunk) * N)[t] = o;
}

// ---- K2: per 64-row chunk. Redundantly computes S = sum(e[b][:]) (4KB, L2-hot),
// ----     bsum from bpart, W = rm0*bsum + rm1*e/S + rm2*f written DIRECTLY to outW,
// ----     and one fused mcW partial per chunk. No atomics, no fences.
__global__ __launch_bounds__(256) void k2(const float* __restrict__ mem,
                                          const float* __restrict__ bpart,
                                          const float* __restrict__ f,
                                          const float* __restrict__ e,
                                          const float* __restrict__ mode,
                                          const int* __restrict__ head,
                                          float* __restrict__ outW,
                                          float* __restrict__ mcW) {
    int bid   = blockIdx.x;
    int b     = bid / CHUNKS_C;
    int chunk = bid % CHUNKS_C;
    int t     = threadIdx.x;
    int lane  = t & 63, wave = t >> 6;
    int r0    = chunk * ROWS_C;

    __shared__ float sred[4];
    __shared__ float bp[4][ROWS_C];
    __shared__ float swv[ROWS_C];
    __shared__ float4 lW[8][32];

    // phase 0: S = sum over e[b][:]
    float4 ev4 = reinterpret_cast<const float4*>(e + (size_t)b * N)[t];
    float es = ev4.x + ev4.y + ev4.z + ev4.w;
#pragma unroll
    for (int off = 32; off; off >>= 1) es += __shfl_down(es, off, 64);
    if (lane == 0) sred[wave] = es;

    // phase 1: bsum partials over CHUNKS_A, split across 4 c-groups
    int n_ = t & 63, cg_ = t >> 6;
    float s = 0.f;
    for (int c = cg_; c < CHUNKS_A; c += 4)
        s += bpart[((size_t)b * CHUNKS_A + c) * N + r0 + n_];
    __syncthreads();          // sred + bp ready after this barrier pair
    bp[cg_][n_] = s;
    __syncthreads();

    float S = sred[0] + sred[1] + sred[2] + sred[3];
    int h = head[0];
    const float* rm = mode + ((size_t)b * H + h) * 3;
    float coef = rm[1] / S;
    if (t < ROWS_C) {
        float bsum = bp[0][t] + bp[1][t] + bp[2][t] + bp[3][t];
        float w = rm[0] * bsum + coef * e[(size_t)b * N + r0 + t]
                + rm[2] * f[(size_t)b * N + r0 + t];
        swv[t] = w;
        outW[(size_t)b * N + r0 + t] = w;
    }
    __syncthreads();

    // phase 2: fused mc partial over this chunk's 64 rows
    int cg = t & 31, rg = t >> 5;
    float4 aW = make_float4(0.f, 0.f, 0.f, 0.f);
#pragma unroll
    for (int rr = 0; rr < ROWS_C / 8; ++rr) {
        int r = rg + rr * 8;
        float4 v = reinterpret_cast<const float4*>(mem + ((size_t)b * N + r0 + r) * M)[cg];
        float ww = swv[r];
        aW.x += ww * v.x; aW.y += ww * v.y; aW.z += ww * v.z; aW.w += ww * v.w;
    }
    lW[rg][cg] = aW;
    __syncthreads();

    if (t < 32) {
        float4 oW = make_float4(0.f, 0.f, 0.f, 0.f);
#pragma unroll
        for (int g = 0; g < 8; ++g) {
            float4 vW = lW[g][t];
            oW.x += vW.x; oW.y += vW.y; oW.z += vW.z; oW.w += vW.w;
        }
        reinterpret_cast<float4*>(mcW + ((size_t)b * CHUNKS_C + chunk) * M)[t] = oW;
    }
}

// ---- K3: outMC[b][m] = sum over chunks of mcW partials (tiny).
__global__ __launch_bounds__(128) void k3(const float* __restrict__ mcW,
                                          float* __restrict__ outMC) {
    int b = blockIdx.x;
    int t = threadIdx.x;   // 128 threads = M
    float s = 0.f;
#pragma unroll
    for (int c = 0; c < CHUNKS_C; ++c)
        s += mcW[((size_t)b * CHUNKS_C + c) * M + t];
    outMC[(size_t)b * M + t] = s;
}

extern "C" void kernel_launch(void* const* d_in, const int* in_sizes, int n_in,
                              void* d_out, int out_size, void* d_ws, size_t ws_size,
                              hipStream_t stream) {
    const float* read_keys      = (const float*)d_in[0];
    const float* read_strengths = (const float*)d_in[1];
    const float* read_mode      = (const float*)d_in[2];
    const float* W_old          = (const float*)d_in[3];
    const float* L              = (const float*)d_in[4];
    const float* memory         = (const float*)d_in[5];
    const int*   head_no        = (const int*)d_in[6];

    float* out_W  = (float*)d_out;             // B*N
    float* out_mc = out_W + (size_t)B * N;     // B*M

    float* ws    = (float*)d_ws;
    float* f     = ws;                                    // B*N
    float* bpart = f + (size_t)B * N;                     // B*CHUNKS_A*N (8 MB)
    float* e     = bpart + (size_t)B * CHUNKS_A * N;      // B*N
    float* mcW   = e + (size_t)B * N;                     // B*CHUNKS_C*M

    k1<<<NBLK_A, 256, 0, stream>>>(L, W_old, memory, read_keys,
                                   read_strengths, head_no, f, bpart, e);
    k2<<<B * CHUNKS_C, 256, 0, stream>>>(memory, bpart, f, e, read_mode, head_no,
                                         out_W, mcW);
    k3<<<B, 128, 0, stream>>>(mcW, out_mc);
}

// Round 7
// 37.275 us; speedup vs baseline: 2.5473x; 1.1000x over previous
//
#include <hip/hip_runtime.h>
#include <math.h>

#define EPS 1e-8f

constexpr int B = 32, N = 1024, M = 128, H = 2;

constexpr int ROWS_A   = 32;            // rows of L (and mem) per block
constexpr int CHUNKS_A = N / ROWS_A;    // 32
constexpr int NBLK_A   = B * CHUNKS_A;  // 1024
constexpr int ROWS_C   = 64;            // rows per k2 block
constexpr int CHUNKS_C = N / ROWS_C;    // 16

// ---- K1: per block (b, chunk): f/bpart over 32 L-rows AND e over 32 mem-rows.
// ----     First 16 blocks also zero outMC (k1 completes before k2 starts).
__global__ __launch_bounds__(256) void k1(const float* __restrict__ L,
                                          const float* __restrict__ Wold,
                                          const float* __restrict__ mem,
                                          const float* __restrict__ keys,
                                          const float* __restrict__ strengths,
                                          const int* __restrict__ head,
                                          float* __restrict__ f,
                                          float* __restrict__ bpart,
                                          float* __restrict__ e,
                                          float* __restrict__ outMC) {
    int bid   = blockIdx.x;
    int t     = threadIdx.x;
    int lane  = t & 63, wave = t >> 6;
    int b     = bid / CHUNKS_A;
    int chunk = bid % CHUNKS_A;
    int r0    = chunk * ROWS_A;

    if (bid < 16) outMC[bid * 256 + t] = 0.f;   // B*M = 4096 = 16*256

    __shared__ float sw[N];
    __shared__ float lds_b[4][N];

    reinterpret_cast<float4*>(sw)[t] =
        reinterpret_cast<const float4*>(Wold + (size_t)b * N)[t];
    __syncthreads();

    float4 wreg[4];
    float4 bacc[4];
#pragma unroll
    for (int s = 0; s < 4; ++s) {
        wreg[s] = reinterpret_cast<float4*>(sw)[lane + 64 * s];
        bacc[s] = make_float4(0.f, 0.f, 0.f, 0.f);
    }

    const float* Lb = L + (size_t)b * N * N;
    for (int r = wave; r < ROWS_A; r += 4) {          // 8 rows per wave
        int i = r0 + r;
        const float4* row = reinterpret_cast<const float4*>(Lb + (size_t)i * N);
        float wi = sw[i];
        float p  = 0.f;
#pragma unroll
        for (int s = 0; s < 4; ++s) {
            float4 v = row[lane + 64 * s];
            p += v.x * wreg[s].x + v.y * wreg[s].y + v.z * wreg[s].z + v.w * wreg[s].w;
            bacc[s].x += v.x * wi;
            bacc[s].y += v.y * wi;
            bacc[s].z += v.z * wi;
            bacc[s].w += v.w * wi;
        }
#pragma unroll
        for (int off = 32; off; off >>= 1) p += __shfl_down(p, off, 64);
        if (lane == 0) f[(size_t)b * N + i] = p;
    }

    // e-work: same 32 rows of memory
    {
        int l32 = lane & 31, half = lane >> 5;
        int h   = head[0];
        float4 kv = reinterpret_cast<const float4*>(keys + ((size_t)b * H + h) * M)[l32];
        float  sk = kv.x * kv.x + kv.y * kv.y + kv.z * kv.z + kv.w * kv.w;
#pragma unroll
        for (int off = 16; off; off >>= 1) sk += __shfl_xor(sk, off, 64);
        float norm_k = sqrtf(sk);
        float beta   = strengths[(size_t)b * H + h];
#pragma unroll
        for (int rr = 0; rr < ROWS_A / 8; ++rr) {     // 4 iters, 2 rows/wave/iter
            int n = r0 + wave * 8 + rr * 2 + half;
            float4 mv = reinterpret_cast<const float4*>(mem + ((size_t)b * N + n) * M)[l32];
            float dot = mv.x * kv.x + mv.y * kv.y + mv.z * kv.z + mv.w * kv.w;
            float sm  = mv.x * mv.x + mv.y * mv.y + mv.z * mv.z + mv.w * mv.w;
#pragma unroll
            for (int off = 16; off; off >>= 1) {
                dot += __shfl_xor(dot, off, 64);
                sm  += __shfl_xor(sm, off, 64);
            }
            if (l32 == 0) {
                float denom = sqrtf(sm) * norm_k + EPS;
                e[(size_t)b * N + n] = expf(beta * dot / denom);
            }
        }
    }

#pragma unroll
    for (int s = 0; s < 4; ++s)
        reinterpret_cast<float4*>(lds_b[wave])[lane + 64 * s] = bacc[s];
    __syncthreads();

    float4 s0 = reinterpret_cast<float4*>(lds_b[0])[t];
    float4 s1 = reinterpret_cast<float4*>(lds_b[1])[t];
    float4 s2 = reinterpret_cast<float4*>(lds_b[2])[t];
    float4 s3 = reinterpret_cast<float4*>(lds_b[3])[t];
    float4 o;
    o.x = s0.x + s1.x + s2.x + s3.x;
    o.y = s0.y + s1.y + s2.y + s3.y;
    o.z = s0.z + s1.z + s2.z + s3.z;
    o.w = s0.w + s1.w + s2.w + s3.w;
    reinterpret_cast<float4*>(bpart + ((size_t)b * CHUNKS_A + chunk) * N)[t] = o;
}

// ---- K2: per 64-row chunk. Redundant S = sum(e[b][:]) (4KB, cache-hot),
// ----     bsum from bpart, W written directly to outW, and the chunk's
// ----     mc partial accumulated into outMC via atomicAdd (16 adds/address).
__global__ __launch_bounds__(256) void k2(const float* __restrict__ mem,
                                          const float* __restrict__ bpart,
                                          const float* __restrict__ f,
                                          const float* __restrict__ e,
                                          const float* __restrict__ mode,
                                          const int* __restrict__ head,
                                          float* __restrict__ outW,
                                          float* __restrict__ outMC) {
    int bid   = blockIdx.x;
    int b     = bid / CHUNKS_C;
    int chunk = bid % CHUNKS_C;
    int t     = threadIdx.x;
    int lane  = t & 63, wave = t >> 6;
    int r0    = chunk * ROWS_C;

    __shared__ float sred[4];
    __shared__ float bp[4][ROWS_C];
    __shared__ float swv[ROWS_C];
    __shared__ float4 lW[8][32];

    // phase 0: S = sum over e[b][:]
    float4 ev4 = reinterpret_cast<const float4*>(e + (size_t)b * N)[t];
    float es = ev4.x + ev4.y + ev4.z + ev4.w;
#pragma unroll
    for (int off = 32; off; off >>= 1) es += __shfl_down(es, off, 64);
    if (lane == 0) sred[wave] = es;

    // phase 1: bsum partials over CHUNKS_A, split across 4 c-groups
    int n_ = t & 63, cg_ = t >> 6;
    float s = 0.f;
#pragma unroll
    for (int c = cg_; c < CHUNKS_A; c += 4)
        s += bpart[((size_t)b * CHUNKS_A + c) * N + r0 + n_];
    __syncthreads();
    bp[cg_][n_] = s;
    __syncthreads();

    float S = sred[0] + sred[1] + sred[2] + sred[3];
    int h = head[0];
    const float* rm = mode + ((size_t)b * H + h) * 3;
    float coef = rm[1] / S;
    if (t < ROWS_C) {
        float bsum = bp[0][t] + bp[1][t] + bp[2][t] + bp[3][t];
        float w = rm[0] * bsum + coef * e[(size_t)b * N + r0 + t]
                + rm[2] * f[(size_t)b * N + r0 + t];
        swv[t] = w;
        outW[(size_t)b * N + r0 + t] = w;
    }
    __syncthreads();

    // phase 2: fused mc partial over this chunk's 64 rows
    int cg = t & 31, rg = t >> 5;
    float4 aW = make_float4(0.f, 0.f, 0.f, 0.f);
#pragma unroll
    for (int rr = 0; rr < ROWS_C / 8; ++rr) {
        int r = rg + rr * 8;
        float4 v = reinterpret_cast<const float4*>(mem + ((size_t)b * N + r0 + r) * M)[cg];
        float ww = swv[r];
        aW.x += ww * v.x; aW.y += ww * v.y; aW.z += ww * v.z; aW.w += ww * v.w;
    }
    lW[rg][cg] = aW;
    __syncthreads();

    if (t < 32) {
        float4 oW = make_float4(0.f, 0.f, 0.f, 0.f);
#pragma unroll
        for (int g = 0; g < 8; ++g) {
            float4 vW = lW[g][t];
            oW.x += vW.x; oW.y += vW.y; oW.z += vW.z; oW.w += vW.w;
        }
        float* dst = outMC + (size_t)b * M + 4 * t;
        atomicAdd(dst + 0, oW.x);
        atomicAdd(dst + 1, oW.y);
        atomicAdd(dst + 2, oW.z);
        atomicAdd(dst + 3, oW.w);
    }
}

extern "C" void kernel_launch(void* const* d_in, const int* in_sizes, int n_in,
                              void* d_out, int out_size, void* d_ws, size_t ws_size,
                              hipStream_t stream) {
    const float* read_keys      = (const float*)d_in[0];
    const float* read_strengths = (const float*)d_in[1];
    const float* read_mode      = (const float*)d_in[2];
    const float* W_old          = (const float*)d_in[3];
    const float* L              = (const float*)d_in[4];
    const float* memory         = (const float*)d_in[5];
    const int*   head_no        = (const int*)d_in[6];

    float* out_W  = (float*)d_out;             // B*N
    float* out_mc = out_W + (size_t)B * N;     // B*M

    float* ws    = (float*)d_ws;
    float* f     = ws;                                    // B*N
    float* bpart = f + (size_t)B * N;                     // B*CHUNKS_A*N (4 MB)
    float* e     = bpart + (size_t)B * CHUNKS_A * N;      // B*N

    k1<<<NBLK_A, 256, 0, stream>>>(L, W_old, memory, read_keys,
                                   read_strengths, head_no, f, bpart, e, out_mc);
    k2<<<B * CHUNKS_C, 256, 0, stream>>>(memory, bpart, f, e, read_mode, head_no,
                                         out_W, out_mc);
}